// Round 1
// baseline (116.674 us; speedup 1.0000x reference)
//
#include <hip/hip_runtime.h>

// RoPE: out[..., 2i]   = cos*x[...,2i] - sin*x[...,2i+1]
//       out[..., 2i+1] = sin*x[...,2i] + cos*x[...,2i+1]
// x: (4,32,4096,128) fp32, sin/cos: (8192,64) fp32, pos: (4*32*4096) int32.
// Memory-bound: ~516 MB traffic -> ~82 us floor at 6.3 TB/s.

__global__ void rope_kernel(const float* __restrict__ x,
                            const float* __restrict__ sinT,
                            const float* __restrict__ cosT,
                            const int* __restrict__ pos,
                            float* __restrict__ out,
                            long long n4) {
    long long idx = (long long)blockIdx.x * blockDim.x + threadIdx.x;
    long long stride = (long long)gridDim.x * blockDim.x;
    for (long long g = idx; g < n4; g += stride) {
        long long row = g >> 5;               // 128 floats/row = 32 float4 groups
        int i0 = ((int)g & 31) << 1;          // even pair index within row, 0..62
        int p = pos[row];                     // broadcast across 32 lanes via cache
        const float2 s = *reinterpret_cast<const float2*>(sinT + (long long)p * 64 + i0);
        const float2 c = *reinterpret_cast<const float2*>(cosT + (long long)p * 64 + i0);
        float4 v = *reinterpret_cast<const float4*>(x + 4 * g);
        float4 r;
        r.x = c.x * v.x - s.x * v.y;
        r.y = s.x * v.x + c.x * v.y;
        r.z = c.y * v.z - s.y * v.w;
        r.w = s.y * v.z + c.y * v.w;
        *reinterpret_cast<float4*>(out + 4 * g) = r;
    }
}

extern "C" void kernel_launch(void* const* d_in, const int* in_sizes, int n_in,
                              void* d_out, int out_size, void* d_ws, size_t ws_size,
                              hipStream_t stream) {
    const float* x    = (const float*)d_in[0];
    const float* sinT = (const float*)d_in[1];
    const float* cosT = (const float*)d_in[2];
    const int*   pos  = (const int*)d_in[3];
    float* out = (float*)d_out;

    long long n4 = (long long)out_size / 4;   // 16,777,216 float4 groups
    const int block = 256;
    int grid = 2048;                          // 256 CU x 8 blocks/CU, grid-stride rest
    rope_kernel<<<grid, block, 0, stream>>>(x, sinT, cosT, pos, out, n4);
}